// Round 8
// baseline (340.230 us; speedup 1.0000x reference)
//
#include <hip/hip_runtime.h>

// log2(1e-7): frac < 1e-7  <=>  log2(frac) < this
#define LOG2_EPS_CLAMP -23.2534966f

__device__ __forceinline__ float flog2(float x) { return __builtin_amdgcn_logf(x); }

// 4 waves/block; wave s owns i in [4s,4s+4) for the block's 64 neurons
// (one neuron per lane). Every global load: 64 consecutive neurons ->
// one 256B segment. Cross-wave reduction via LDS (no shuffles).
__global__ __launch_bounds__(256) void pid_kernel(const float* __restrict__ p,
                                                  float* __restrict__ out,
                                                  const int N) {
    __shared__ float m12buf[32][64];     // full m12, built with ds atomics (8 KB)
    __shared__ float ibuf[3][4][64];     // I1/I2/I4 per-wave partials (3 KB)

    const int tid = threadIdx.x;
    const int g   = tid & 63;            // lane -> neuron offset in block
    const int s   = tid >> 6;            // wave -> i-group
    const int n   = blockIdx.x * 64 + g;
    const bool active = (n < N);

    // zero the atomic target
    #pragma unroll
    for (int t = 0; t < 8; ++t) ((float*)m12buf)[t * 256 + tid] = 0.f;
    __syncthreads();

    const float* __restrict__ q = p + n;

    float a0[4], a1[4];                  // own-i m02 slices
    float part[32];                      // partial m12 over own 4 i's
    #pragma unroll
    for (int t = 0; t < 32; ++t) part[t] = 0.f;

    // ---- phase 1: partial marginals (perfectly coalesced loads) ----
    if (active) {
        #pragma unroll
        for (int ii = 0; ii < 4; ++ii) {
            const int i = s * 4 + ii;
            const float* __restrict__ qi = q + (size_t)(i * 32) * (size_t)N;
            float s0 = 0.f, s1 = 0.f;
            #pragma unroll
            for (int j = 0; j < 16; ++j) {
                const float f0 = qi[(size_t)(2 * j) * (size_t)N];
                const float f1 = qi[(size_t)(2 * j + 1) * (size_t)N];
                s0 += f0; s1 += f1;
                part[2 * j]     += f0;
                part[2 * j + 1] += f1;
            }
            a0[ii] = s0; a1[ii] = s1;
        }
        #pragma unroll
        for (int t = 0; t < 32; ++t) atomicAdd(&m12buf[t][g], part[t]);
    }
    __syncthreads();

    // full m12 into registers (bank = g%32, 2-way -> free)
    float m12[32];
    #pragma unroll
    for (int t = 0; t < 32; ++t) m12[t] = m12buf[t][g];

    float P20 = 0.f, P21 = 0.f;
    #pragma unroll
    for (int j = 0; j < 16; ++j) { P20 += m12[2 * j]; P21 += m12[2 * j + 1]; }
    const float LP20 = flog2(P20);
    const float LP21 = flog2(P21);

    // ---- phase 2: I1 ({0}{1}), I4 ({01}), I2 over own i's (L2/L3-hit reloads) ----
    float I1 = 0.f, I2 = 0.f, I4 = 0.f;
    if (active) {
        #pragma unroll
        for (int ii = 0; ii < 4; ++ii) {
            const int i = s * 4 + ii;
            const float a0i = a0[ii], a1i = a1[ii];
            const float m0i = a0i + a1i;
            const float* __restrict__ qi = q + (size_t)(i * 32) * (size_t)N;
            #pragma unroll
            for (int j = 0; j < 16; ++j) {
                const float f0  = qi[(size_t)(2 * j) * (size_t)N];
                const float f1  = qi[(size_t)(2 * j + 1) * (size_t)N];
                const float p01 = f0 + f1;
                const float m1j = m12[2 * j] + m12[2 * j + 1];
                const float u1  = m0i + m1j - p01;
                const float Lu1  = flog2(u1);
                const float Lp01 = flog2(p01);
                // k = 0
                {
                    const float num = a0i + m12[2 * j] - f0;
                    float l1 = flog2(num) - Lu1 - LP20;
                    l1 = (l1 < LOG2_EPS_CLAMP) ? 0.f : l1;
                    I1 = fmaf(f0, l1, I1);
                    float l4 = flog2(f0) - Lp01 - LP20;
                    l4 = (l4 < LOG2_EPS_CLAMP) ? 0.f : l4;
                    I4 = fmaf(f0, l4, I4);
                }
                // k = 1
                {
                    const float num = a1i + m12[2 * j + 1] - f1;
                    float l1 = flog2(num) - Lu1 - LP21;
                    l1 = (l1 < LOG2_EPS_CLAMP) ? 0.f : l1;
                    I1 = fmaf(f1, l1, I1);
                    float l4 = flog2(f1) - Lp01 - LP21;
                    l4 = (l4 < LOG2_EPS_CLAMP) ? 0.f : l4;
                    I4 = fmaf(f1, l4, I4);
                }
            }
            // I2 contribution of this i
            const float L0 = flog2(m0i);
            float la = flog2(a0i) - L0 - LP20;
            la = (la < LOG2_EPS_CLAMP) ? 0.f : la;
            I2 = fmaf(a0i, la, I2);
            float lb = flog2(a1i) - L0 - LP21;
            lb = (lb < LOG2_EPS_CLAMP) ? 0.f : lb;
            I2 = fmaf(a1i, lb, I2);
        }
    }
    ibuf[0][s][g] = I1;
    ibuf[1][s][g] = I2;
    ibuf[2][s][g] = I4;
    __syncthreads();

    if (s == 0 && active) {
        I1 = ibuf[0][0][g] + ibuf[0][1][g] + ibuf[0][2][g] + ibuf[0][3][g];
        I2 = ibuf[1][0][g] + ibuf[1][1][g] + ibuf[1][2][g] + ibuf[1][3][g];
        I4 = ibuf[2][0][g] + ibuf[2][1][g] + ibuf[2][2][g] + ibuf[2][3][g];

        // I3 = I(X1;Y) from full m12
        float I3 = 0.f;
        #pragma unroll
        for (int j = 0; j < 16; ++j) {
            const float L1 = flog2(m12[2 * j] + m12[2 * j + 1]);
            float la = flog2(m12[2 * j]) - L1 - LP20;
            la = (la < LOG2_EPS_CLAMP) ? 0.f : la;
            I3 = fmaf(m12[2 * j], la, I3);
            float lb = flog2(m12[2 * j + 1]) - L1 - LP21;
            lb = (lb < LOG2_EPS_CLAMP) ? 0.f : lb;
            I3 = fmaf(m12[2 * j + 1], lb, I3);
        }
        const float H = -(P20 * flog2(P20 + 1e-10f) + P21 * flog2(P21 + 1e-10f));

        out[0 * N + n] = I1;
        out[1 * N + n] = I2 - I1;
        out[2 * N + n] = I3 - I1;
        out[3 * N + n] = I1 - I2 - I3 + I4;
        out[4 * N + n] = H - I4;
    }
}

extern "C" void kernel_launch(void* const* d_in, const int* in_sizes, int n_in,
                              void* d_out, int out_size, void* d_ws, size_t ws_size,
                              hipStream_t stream) {
    const float* p = (const float*)d_in[0];
    float* out = (float*)d_out;
    const int N = in_sizes[0] / 512;          // (16*16*2) bins per neuron
    const int blocks = (N + 63) / 64;         // 64 neurons per 256-thread block
    pid_kernel<<<blocks, 256, 0, stream>>>(p, out, N);
}